// Round 2
// baseline (546.794 us; speedup 1.0000x reference)
//
#include <hip/hip_runtime.h>
#include <math.h>

#define BATCH 512

__device__ __forceinline__ float elu1(float v) {
    return v > 0.f ? v : expm1f(v);
}
__device__ __forceinline__ float4 elu4(float4 v) {
    return make_float4(elu1(v.x), elu1(v.y), elu1(v.z), elu1(v.w));
}

// ============ Kernel 1: conv1 (9-dir stencil, 1->32) + ELU + 2x2 pool ============
// block = 1 image (256 thr). LDS: zero-padded x [30][30] + weights.
__global__ __launch_bounds__(256) void k1_conv1_pool(
    const float* __restrict__ x, const float* __restrict__ W1,
    const float* __restrict__ root1, const float* __restrict__ b1,
    float* __restrict__ p1) {
    __shared__ float xs[900];            // [30][30] zero-padded image
    __shared__ float w1s[8 * 32 + 64];   // 8 dir matrices [8][32], root[32], b[32]
    const int b = blockIdx.x;
    const int t = threadIdx.x;

    // zero pad + stage weights
    for (int l = t; l < 900; l += 256) xs[l] = 0.f;
    {
        int d = t >> 5, c = t & 31;
        int e = d + (d >= 4 ? 1 : 0);
        int dy = e / 3 - 1, dx = e % 3 - 1;
        int widx = 2 * (dx + 1) + 10 * (dy + 1);
        w1s[t] = W1[widx * 32 + c];
        if (t < 32) { w1s[256 + t] = root1[t]; w1s[288 + t] = b1[t]; }
    }
    __syncthreads();
    // interior
    const float* xb = x + (size_t)b * 784;
    for (int l = t; l < 784; l += 256) {
        int y = l / 28, xx = l % 28;
        xs[(y + 1) * 30 + xx + 1] = xb[l];
    }
    __syncthreads();

    if (t >= 196) return;
    int py = t / 14, px = t % 14;
    int xbse[4];
    float xc[4], inv[4];
    #pragma unroll
    for (int p = 0; p < 4; ++p) {
        int sy = p >> 1, sx = p & 1;
        int y = 2 * py + sy, xx = 2 * px + sx;
        xbse[p] = (y + 1) * 30 + xx + 1;
        xc[p] = xs[xbse[p]];
        int nvy = 3 - (y == 0) - (y == 27);
        int nvx = 3 - (xx == 0) - (xx == 27);
        inv[p] = 1.f / (float)(nvy * nvx - 1);
    }
    const float4* w4 = (const float4*)w1s;
    float* outp = p1 + ((size_t)b * 196 + t) * 32;

    #pragma unroll
    for (int h = 0; h < 2; ++h) {          // channel halves of 16
        float4 acc[4][4];
        #pragma unroll
        for (int p = 0; p < 4; ++p)
            #pragma unroll
            for (int q = 0; q < 4; ++q) acc[p][q] = make_float4(0.f, 0.f, 0.f, 0.f);
        #pragma unroll
        for (int d = 0; d < 8; ++d) {
            int e = d + (d >= 4 ? 1 : 0);
            int od = (e / 3 - 1) * 30 + (e % 3 - 1);
            float4 w0 = w4[d * 8 + h * 4 + 0];
            float4 w1 = w4[d * 8 + h * 4 + 1];
            float4 w2 = w4[d * 8 + h * 4 + 2];
            float4 w3 = w4[d * 8 + h * 4 + 3];
            #pragma unroll
            for (int p = 0; p < 4; ++p) {
                float xv = xs[xbse[p] + od];
                acc[p][0].x += xv * w0.x; acc[p][0].y += xv * w0.y; acc[p][0].z += xv * w0.z; acc[p][0].w += xv * w0.w;
                acc[p][1].x += xv * w1.x; acc[p][1].y += xv * w1.y; acc[p][1].z += xv * w1.z; acc[p][1].w += xv * w1.w;
                acc[p][2].x += xv * w2.x; acc[p][2].y += xv * w2.y; acc[p][2].z += xv * w2.z; acc[p][2].w += xv * w2.w;
                acc[p][3].x += xv * w3.x; acc[p][3].y += xv * w3.y; acc[p][3].z += xv * w3.z; acc[p][3].w += xv * w3.w;
            }
        }
        #pragma unroll
        for (int q = 0; q < 4; ++q) {
            float4 rt = w4[64 + h * 4 + q];
            float4 bs = w4[72 + h * 4 + q];
            float4 m = make_float4(-1e30f, -1e30f, -1e30f, -1e30f);
            #pragma unroll
            for (int p = 0; p < 4; ++p) {
                float4 v;
                v.x = elu1(acc[p][q].x * inv[p] + xc[p] * rt.x + bs.x);
                v.y = elu1(acc[p][q].y * inv[p] + xc[p] * rt.y + bs.y);
                v.z = elu1(acc[p][q].z * inv[p] + xc[p] * rt.z + bs.z);
                v.w = elu1(acc[p][q].w * inv[p] + xc[p] * rt.w + bs.w);
                m.x = fmaxf(m.x, v.x); m.y = fmaxf(m.y, v.y);
                m.z = fmaxf(m.z, v.z); m.w = fmaxf(m.w, v.w);
            }
            *(float4*)(outp + h * 16 + q * 4) = m;
        }
    }
}

// ============ Kernel 2: conv2 (9-dir, 32->64) + ELU + 2x2 pool ============
// block = 1 image, 256 thr. LDS: padded x [16][16][36] + dbl-buffered W + convout alias.
__global__ __launch_bounds__(256) void k2_conv2_pool(
    const float* __restrict__ p1, const float* __restrict__ W2,
    const float* __restrict__ root2, const float* __restrict__ b2,
    float* __restrict__ p2) {
    __shared__ float smem[13312];   // xs: [0,9216) ; wbuf: [9216, 13312)
    float* xs = smem;
    float* wb = smem + 9216;
    const int b = blockIdx.x;
    const int t = threadIdx.x;
    const int cg = t & 15, g = t >> 4;

    // ---- stage: zero xs, wbuf[0] = W2 dir0 (widx 0)
    {
        float4 z4 = make_float4(0.f, 0.f, 0.f, 0.f);
        float4* xs4 = (float4*)xs;
        #pragma unroll
        for (int i = 0; i < 9; ++i) xs4[t + 256 * i] = z4;
        const float4* s4 = (const float4*)W2;
        float4* w4p = (float4*)wb;
        w4p[t] = s4[t]; w4p[t + 256] = s4[t + 256];
    }
    __syncthreads();
    // interior x
    {
        const float4* p14 = (const float4*)(p1 + (size_t)b * 196 * 32);
        for (int l = t; l < 1568; l += 256) {
            int node = l >> 3, i4 = l & 7;
            int y = node / 14, xx = node - y * 14;
            *(float4*)(xs + ((y + 1) * 16 + xx + 1) * 36 + i4 * 4) = p14[l];
        }
    }
    __syncthreads();

    // node assignment: nodes g*13 + r, r=0..12 (196 valid of 208)
    int nbase[13];
    #pragma unroll
    for (int r = 0; r < 13; ++r) {
        int nn = g * 13 + r;
        if (nn > 195) nn = 195;
        int y = nn / 14, xx = nn - y * 14;
        nbase[r] = (y + 1) * 16 + xx + 1;
    }
    float4 acc[13];
    #pragma unroll
    for (int r = 0; r < 13; ++r) acc[r] = make_float4(0.f, 0.f, 0.f, 0.f);

    for (int d = 0; d < 9; ++d) {
        // prefetch next weight matrix to regs
        float4 pf0, pf1;
        if (d < 8) {
            int nd = d + 1;
            const float* nsrc;
            if (nd == 8) nsrc = root2;
            else {
                int e = nd + (nd >= 4 ? 1 : 0);
                int dy = e / 3 - 1, dx = e % 3 - 1;
                nsrc = W2 + (size_t)(2 * (dx + 1) + 10 * (dy + 1)) * 2048;
            }
            pf0 = ((const float4*)nsrc)[t];
            pf1 = ((const float4*)nsrc)[t + 256];
        }
        if (d == 8) {
            // scale neighbor sums by 1/deg before adding root contribution
            #pragma unroll
            for (int r = 0; r < 13; ++r) {
                int y = (nbase[r] >> 4) - 1, xx = (nbase[r] & 15) - 1;
                int nvy = 3 - (y == 0) - (y == 13);
                int nvx = 3 - (xx == 0) - (xx == 13);
                float iv = 1.f / (float)(nvy * nvx - 1);
                acc[r].x *= iv; acc[r].y *= iv; acc[r].z *= iv; acc[r].w *= iv;
            }
        }
        int od = 0;
        if (d < 8) {
            int e = d + (d >= 4 ? 1 : 0);
            od = (e / 3 - 1) * 16 + (e % 3 - 1);
        }
        const float* wcur = wb + (d & 1) * 2048;
        #pragma unroll
        for (int i4 = 0; i4 < 8; ++i4) {
            float4 w0 = *(const float4*)(wcur + (i4 * 4 + 0) * 64 + cg * 4);
            float4 w1 = *(const float4*)(wcur + (i4 * 4 + 1) * 64 + cg * 4);
            float4 w2 = *(const float4*)(wcur + (i4 * 4 + 2) * 64 + cg * 4);
            float4 w3 = *(const float4*)(wcur + (i4 * 4 + 3) * 64 + cg * 4);
            #pragma unroll
            for (int r = 0; r < 13; ++r) {
                float4 xv = *(const float4*)(xs + (nbase[r] + od) * 36 + i4 * 4);
                acc[r].x += xv.x * w0.x + xv.y * w1.x + xv.z * w2.x + xv.w * w3.x;
                acc[r].y += xv.x * w0.y + xv.y * w1.y + xv.z * w2.y + xv.w * w3.y;
                acc[r].z += xv.x * w0.z + xv.y * w1.z + xv.z * w2.z + xv.w * w3.z;
                acc[r].w += xv.x * w0.w + xv.y * w1.w + xv.z * w2.w + xv.w * w3.w;
            }
        }
        if (d < 8) {
            float4* wn = (float4*)(wb + ((d + 1) & 1) * 2048);
            wn[t] = pf0; wn[t + 256] = pf1;
        }
        __syncthreads();
    }

    // ---- epilogue: bias + ELU -> convout in LDS (alias), then pool
    float4 bias4 = *(const float4*)(b2 + cg * 4);
    float* co = smem;   // [196][64]
    #pragma unroll
    for (int r = 0; r < 13; ++r) {
        int nn = g * 13 + r;
        if (nn < 196) {
            float4 v;
            v.x = elu1(acc[r].x + bias4.x);
            v.y = elu1(acc[r].y + bias4.y);
            v.z = elu1(acc[r].z + bias4.z);
            v.w = elu1(acc[r].w + bias4.w);
            *(float4*)(co + nn * 64 + cg * 4) = v;
        }
    }
    __syncthreads();
    float* outp = p2 + (size_t)b * 3136;
    for (int l = t; l < 3136; l += 256) {
        int o = l & 63, cell = l >> 6;
        int pyy = cell / 7, pxx = cell - pyy * 7;
        int n00 = (2 * pyy) * 14 + 2 * pxx;
        float m = fmaxf(fmaxf(co[n00 * 64 + o], co[(n00 + 1) * 64 + o]),
                        fmaxf(co[(n00 + 14) * 64 + o], co[(n00 + 15) * 64 + o]));
        outp[l] = m;
    }
}

// ============ Kernel 3a: fc1 split-K GEMM. 64x64 tile, BK=16, KS=8 ============
// A = p2 [512][3136], B = fc1_w [3136][512], partials -> part[ks][512][512]
__global__ __launch_bounds__(256) void k3a_fc1(
    const float* __restrict__ A, const float* __restrict__ B,
    float* __restrict__ part) {
    __shared__ float As[16 * 64];
    __shared__ float Bs[16 * 64];
    const int t = threadIdx.x;
    const int tx = t & 15, ty = t >> 4;
    const int n0 = blockIdx.x * 64, m0 = blockIdx.y * 64, kz = blockIdx.z;
    const int nchunk = (kz < 4) ? 25 : 24;                 // 16-float chunks
    const int c0 = (kz < 4) ? kz * 25 : 100 + (kz - 4) * 24;

    const float* Abase = A + (size_t)m0 * 3136 + c0 * 16;
    const float* Bbase = B + (size_t)c0 * 16 * 512 + n0;

    float4 accr[4];
    #pragma unroll
    for (int r = 0; r < 4; ++r) accr[r] = make_float4(0.f, 0.f, 0.f, 0.f);

    const int ma = t >> 2, kqa = t & 3;     // A staging role
    const int kb = t >> 4, n4 = t & 15;     // B staging role

    for (int kk = 0; kk < nchunk; ++kk) {
        float4 av = *(const float4*)(Abase + (size_t)ma * 3136 + kk * 16 + kqa * 4);
        float4 bv = *(const float4*)(Bbase + (size_t)(kk * 16 + kb) * 512 + n4 * 4);
        As[(kqa * 4 + 0) * 64 + ma] = av.x;
        As[(kqa * 4 + 1) * 64 + ma] = av.y;
        As[(kqa * 4 + 2) * 64 + ma] = av.z;
        As[(kqa * 4 + 3) * 64 + ma] = av.w;
        *(float4*)&Bs[kb * 64 + n4 * 4] = bv;
        __syncthreads();
        #pragma unroll
        for (int k = 0; k < 16; ++k) {
            float4 a4 = *(const float4*)&As[k * 64 + ty * 4];
            float4 b4 = *(const float4*)&Bs[k * 64 + tx * 4];
            accr[0].x += a4.x * b4.x; accr[0].y += a4.x * b4.y; accr[0].z += a4.x * b4.z; accr[0].w += a4.x * b4.w;
            accr[1].x += a4.y * b4.x; accr[1].y += a4.y * b4.y; accr[1].z += a4.y * b4.z; accr[1].w += a4.y * b4.w;
            accr[2].x += a4.z * b4.x; accr[2].y += a4.z * b4.y; accr[2].z += a4.z * b4.z; accr[2].w += a4.z * b4.w;
            accr[3].x += a4.w * b4.x; accr[3].y += a4.w * b4.y; accr[3].z += a4.w * b4.z; accr[3].w += a4.w * b4.w;
        }
        __syncthreads();
    }
    #pragma unroll
    for (int r = 0; r < 4; ++r)
        *(float4*)(part + ((size_t)kz * 512 + m0 + ty * 4 + r) * 512 + n0 + tx * 4) = accr[r];
}

// ============ Kernel 3b: reduce partials + bias + ELU ============
__global__ __launch_bounds__(256) void k3b_reduce(
    const float* __restrict__ part, const float* __restrict__ bias,
    float* __restrict__ h3) {
    int gid = blockIdx.x * 256 + threadIdx.x;      // 0..65535 float4s
    const float4* p4 = (const float4*)part;
    float4 s = make_float4(0.f, 0.f, 0.f, 0.f);
    #pragma unroll
    for (int kz = 0; kz < 8; ++kz) {
        float4 v = p4[(size_t)kz * 65536 + gid];
        s.x += v.x; s.y += v.y; s.z += v.z; s.w += v.w;
    }
    float4 b4 = *(const float4*)(bias + (gid & 127) * 4);
    s.x += b4.x; s.y += b4.y; s.z += b4.z; s.w += b4.w;
    ((float4*)h3)[gid] = elu4(s);
}

// ============ Kernel 4: fc2 (512->10) + ELU + log_softmax ============
// lane l holds w rows {l+64j}; per row: coalesced h loads + butterfly reduce.
__global__ __launch_bounds__(256) void k4_fc2_lsm(
    const float* __restrict__ h, const float* __restrict__ w,
    const float* __restrict__ bias, float* __restrict__ out) {
    const int t = threadIdx.x, lane = t & 63;
    const int wv = (blockIdx.x * 256 + t) >> 6;   // global wave id 0..63
    float wl[8][10];
    #pragma unroll
    for (int j = 0; j < 8; ++j)
        #pragma unroll
        for (int o = 0; o < 10; ++o) wl[j][o] = w[(lane + 64 * j) * 10 + o];
    float bo[10];
    #pragma unroll
    for (int o = 0; o < 10; ++o) bo[o] = bias[o];

    for (int row = wv; row < 512; row += 64) {
        float acc[10];
        #pragma unroll
        for (int o = 0; o < 10; ++o) acc[o] = 0.f;
        #pragma unroll
        for (int j = 0; j < 8; ++j) {
            float hv = h[(size_t)row * 512 + lane + 64 * j];
            #pragma unroll
            for (int o = 0; o < 10; ++o) acc[o] += hv * wl[j][o];
        }
        #pragma unroll
        for (int s = 32; s; s >>= 1)
            #pragma unroll
            for (int o = 0; o < 10; ++o) acc[o] += __shfl_xor(acc[o], s, 64);
        float v[10], m = -1e30f;
        #pragma unroll
        for (int o = 0; o < 10; ++o) { v[o] = elu1(acc[o] + bo[o]); m = fmaxf(m, v[o]); }
        float ssum = 0.f;
        #pragma unroll
        for (int o = 0; o < 10; ++o) ssum += expf(v[o] - m);
        float lse = m + logf(ssum);
        if (lane < 10) {
            float val = v[0];
            #pragma unroll
            for (int o = 1; o < 10; ++o) val = (lane == o) ? v[o] : val;
            out[(size_t)row * 10 + lane] = val - lse;
        }
    }
}

extern "C" void kernel_launch(void* const* d_in, const int* in_sizes, int n_in,
                              void* d_out, int out_size, void* d_ws, size_t ws_size,
                              hipStream_t stream) {
    const float* x     = (const float*)d_in[0];
    const float* W1    = (const float*)d_in[3];
    const float* root1 = (const float*)d_in[4];
    const float* b1v   = (const float*)d_in[5];
    const float* W2    = (const float*)d_in[6];
    const float* root2 = (const float*)d_in[7];
    const float* b2v   = (const float*)d_in[8];
    const float* fc1w  = (const float*)d_in[9];
    const float* fc1b  = (const float*)d_in[10];
    const float* fc2w  = (const float*)d_in[11];
    const float* fc2b  = (const float*)d_in[12];

    float* ws = (float*)d_ws;
    float* p1 = ws;                                   // 512*196*32 = 3,211,264 f
    float* p2 = p1 + (size_t)BATCH * 196 * 32;        // 512*49*64  = 1,605,632 f
    float* h3 = p2 + (size_t)BATCH * 49 * 64;         // 512*512    =   262,144 f
    float* part = p1;                                 // alias: p1 dead after k2 (needs 2,097,152 f)

    k1_conv1_pool<<<dim3(BATCH), 256, 0, stream>>>(x, W1, root1, b1v, p1);
    k2_conv2_pool<<<dim3(BATCH), 256, 0, stream>>>(p1, W2, root2, b2v, p2);
    k3a_fc1<<<dim3(8, 8, 8), 256, 0, stream>>>(p2, fc1w, part);
    k3b_reduce<<<dim3(256), 256, 0, stream>>>(part, fc1b, h3);
    k4_fc2_lsm<<<dim3(16), 256, 0, stream>>>(h3, fc2w, fc2b, (float*)d_out);
}

// Round 3
// 137.666 us; speedup vs baseline: 3.9719x; 3.9719x over previous
//
#include <hip/hip_runtime.h>
#include <math.h>

#define BATCH 512

__device__ __forceinline__ float elu1(float v) {
    return v > 0.f ? v : expm1f(v);
}
__device__ __forceinline__ float4 elu4(float4 v) {
    return make_float4(elu1(v.x), elu1(v.y), elu1(v.z), elu1(v.w));
}

// ============ Kernel 1: conv1 (9-dir stencil, 1->32) + ELU + 2x2 pool ============
// block = 1 image (256 thr). LDS: zero-padded x [30][30] + weights.
__global__ __launch_bounds__(256) void k1_conv1_pool(
    const float* __restrict__ x, const float* __restrict__ W1,
    const float* __restrict__ root1, const float* __restrict__ b1,
    float* __restrict__ p1) {
    __shared__ float xs[900];            // [30][30] zero-padded image
    __shared__ float w1s[8 * 32 + 64];   // 8 dir matrices [8][32], root[32], b[32]
    const int b = blockIdx.x;
    const int t = threadIdx.x;

    for (int l = t; l < 900; l += 256) xs[l] = 0.f;
    {
        int d = t >> 5, c = t & 31;
        int e = d + (d >= 4 ? 1 : 0);
        int dy = e / 3 - 1, dx = e % 3 - 1;
        int widx = 2 * (dx + 1) + 10 * (dy + 1);
        w1s[t] = W1[widx * 32 + c];
        if (t < 32) { w1s[256 + t] = root1[t]; w1s[288 + t] = b1[t]; }
    }
    __syncthreads();
    const float* xb = x + (size_t)b * 784;
    for (int l = t; l < 784; l += 256) {
        int y = l / 28, xx = l % 28;
        xs[(y + 1) * 30 + xx + 1] = xb[l];
    }
    __syncthreads();

    if (t >= 196) return;
    int py = t / 14, px = t % 14;
    int xbse[4];
    float xc[4], inv[4];
    #pragma unroll
    for (int p = 0; p < 4; ++p) {
        int sy = p >> 1, sx = p & 1;
        int y = 2 * py + sy, xx = 2 * px + sx;
        xbse[p] = (y + 1) * 30 + xx + 1;
        xc[p] = xs[xbse[p]];
        int nvy = 3 - (y == 0) - (y == 27);
        int nvx = 3 - (xx == 0) - (xx == 27);
        inv[p] = 1.f / (float)(nvy * nvx - 1);
    }
    const float4* w4 = (const float4*)w1s;
    float* outp = p1 + ((size_t)b * 196 + t) * 32;

    #pragma unroll
    for (int h = 0; h < 2; ++h) {          // channel halves of 16
        float4 acc[4][4];
        #pragma unroll
        for (int p = 0; p < 4; ++p)
            #pragma unroll
            for (int q = 0; q < 4; ++q) acc[p][q] = make_float4(0.f, 0.f, 0.f, 0.f);
        #pragma unroll
        for (int d = 0; d < 8; ++d) {
            int e = d + (d >= 4 ? 1 : 0);
            int od = (e / 3 - 1) * 30 + (e % 3 - 1);
            float4 w0 = w4[d * 8 + h * 4 + 0];
            float4 w1 = w4[d * 8 + h * 4 + 1];
            float4 w2 = w4[d * 8 + h * 4 + 2];
            float4 w3 = w4[d * 8 + h * 4 + 3];
            #pragma unroll
            for (int p = 0; p < 4; ++p) {
                float xv = xs[xbse[p] + od];
                acc[p][0].x += xv * w0.x; acc[p][0].y += xv * w0.y; acc[p][0].z += xv * w0.z; acc[p][0].w += xv * w0.w;
                acc[p][1].x += xv * w1.x; acc[p][1].y += xv * w1.y; acc[p][1].z += xv * w1.z; acc[p][1].w += xv * w1.w;
                acc[p][2].x += xv * w2.x; acc[p][2].y += xv * w2.y; acc[p][2].z += xv * w2.z; acc[p][2].w += xv * w2.w;
                acc[p][3].x += xv * w3.x; acc[p][3].y += xv * w3.y; acc[p][3].z += xv * w3.z; acc[p][3].w += xv * w3.w;
            }
        }
        #pragma unroll
        for (int q = 0; q < 4; ++q) {
            float4 rt = w4[64 + h * 4 + q];
            float4 bs = w4[72 + h * 4 + q];
            float4 m = make_float4(-1e30f, -1e30f, -1e30f, -1e30f);
            #pragma unroll
            for (int p = 0; p < 4; ++p) {
                float4 v;
                v.x = elu1(acc[p][q].x * inv[p] + xc[p] * rt.x + bs.x);
                v.y = elu1(acc[p][q].y * inv[p] + xc[p] * rt.y + bs.y);
                v.z = elu1(acc[p][q].z * inv[p] + xc[p] * rt.z + bs.z);
                v.w = elu1(acc[p][q].w * inv[p] + xc[p] * rt.w + bs.w);
                m.x = fmaxf(m.x, v.x); m.y = fmaxf(m.y, v.y);
                m.z = fmaxf(m.z, v.z); m.w = fmaxf(m.w, v.w);
            }
            *(float4*)(outp + h * 16 + q * 4) = m;
        }
    }
}

// ============ Kernel 2: conv2 (9-dir, 32->64) + ELU + 2x2 pool ============
// block = 1 image, 256 thr. thread = 1 pooled cell x 16 channels; pool in regs.
// LDS: xs zero-padded [16*16 nodes][stride 33] + W double-buffer [2][2048].
__global__ __launch_bounds__(256) void k2_conv2_pool(
    const float* __restrict__ p1, const float* __restrict__ W2,
    const float* __restrict__ root2, const float* __restrict__ b2,
    float* __restrict__ p2) {
    __shared__ float xs[8448];         // 256 nodes * 33
    __shared__ float wb[2][2048];      // [32][64] per direction
    const int b = blockIdx.x;
    const int t = threadIdx.x;
    const int cell = t >> 2, cg = t & 3;

    // stage dir-0 weights (widx 0 is first matrix of W2)
    {
        const float4* s4 = (const float4*)W2;
        float4* w4p = (float4*)wb[0];
        w4p[t] = s4[t]; w4p[t + 256] = s4[t + 256];
    }
    // zero xs
    for (int l = t; l < 8448; l += 256) xs[l] = 0.f;
    __syncthreads();
    // interior fill: p1 is [b][196][32] node-major
    {
        const float* src = p1 + (size_t)b * 6272;
        for (int l = t; l < 6272; l += 256) {
            int node = l >> 5, i = l & 31;
            int y = node / 14, xx = node - y * 14;
            xs[((y + 1) * 16 + xx + 1) * 33 + i] = src[l];
        }
    }
    __syncthreads();

    const int ccell = (cell < 49) ? cell : 48;
    const int py = ccell / 7, px = ccell - py * 7;
    int nb[4];
    float inv[4];
    #pragma unroll
    for (int p = 0; p < 4; ++p) {
        int sy = p >> 1, sx = p & 1;
        int y = 2 * py + sy, xx = 2 * px + sx;
        nb[p] = ((y + 1) * 16 + xx + 1) * 33;
        int nvy = 3 - (y == 0) - (y == 13);
        int nvx = 3 - (xx == 0) - (xx == 13);
        inv[p] = 1.f / (float)(nvy * nvx - 1);
    }

    float4 acc[4][4];
    #pragma unroll
    for (int p = 0; p < 4; ++p)
        #pragma unroll
        for (int q = 0; q < 4; ++q) acc[p][q] = make_float4(0.f, 0.f, 0.f, 0.f);

    for (int d = 0; d < 9; ++d) {
        // prefetch next direction's weights into registers
        float4 pf0, pf1;
        if (d < 8) {
            int nd = d + 1;
            const float* nsrc;
            if (nd == 8) nsrc = root2;
            else {
                int e = nd + (nd >= 4 ? 1 : 0);
                int dy = e / 3 - 1, dx = e % 3 - 1;
                nsrc = W2 + (size_t)(2 * (dx + 1) + 10 * (dy + 1)) * 2048;
            }
            pf0 = ((const float4*)nsrc)[t];
            pf1 = ((const float4*)nsrc)[t + 256];
        }
        if (d == 8) {
            // scale neighbor sums by 1/deg before root contribution
            #pragma unroll
            for (int p = 0; p < 4; ++p) {
                acc[p][0].x *= inv[p]; acc[p][0].y *= inv[p]; acc[p][0].z *= inv[p]; acc[p][0].w *= inv[p];
                acc[p][1].x *= inv[p]; acc[p][1].y *= inv[p]; acc[p][1].z *= inv[p]; acc[p][1].w *= inv[p];
                acc[p][2].x *= inv[p]; acc[p][2].y *= inv[p]; acc[p][2].z *= inv[p]; acc[p][2].w *= inv[p];
                acc[p][3].x *= inv[p]; acc[p][3].y *= inv[p]; acc[p][3].z *= inv[p]; acc[p][3].w *= inv[p];
            }
        }
        int od33 = 0;
        if (d < 8) {
            int e = d + (d >= 4 ? 1 : 0);
            od33 = ((e / 3 - 1) * 16 + (e % 3 - 1)) * 33;
        }
        const float* wcur = wb[d & 1] + cg * 16;
        const float* xc0 = xs + nb[0] + od33;
        const float* xc1 = xs + nb[1] + od33;
        const float* xc2 = xs + nb[2] + od33;
        const float* xc3 = xs + nb[3] + od33;
        #pragma unroll 2
        for (int i = 0; i < 32; ++i) {
            float4 w0 = *(const float4*)(wcur + i * 64 + 0);
            float4 w1 = *(const float4*)(wcur + i * 64 + 4);
            float4 w2 = *(const float4*)(wcur + i * 64 + 8);
            float4 w3 = *(const float4*)(wcur + i * 64 + 12);
            float x0 = xc0[i], x1 = xc1[i], x2 = xc2[i], x3 = xc3[i];
            acc[0][0].x += x0 * w0.x; acc[0][0].y += x0 * w0.y; acc[0][0].z += x0 * w0.z; acc[0][0].w += x0 * w0.w;
            acc[0][1].x += x0 * w1.x; acc[0][1].y += x0 * w1.y; acc[0][1].z += x0 * w1.z; acc[0][1].w += x0 * w1.w;
            acc[0][2].x += x0 * w2.x; acc[0][2].y += x0 * w2.y; acc[0][2].z += x0 * w2.z; acc[0][2].w += x0 * w2.w;
            acc[0][3].x += x0 * w3.x; acc[0][3].y += x0 * w3.y; acc[0][3].z += x0 * w3.z; acc[0][3].w += x0 * w3.w;
            acc[1][0].x += x1 * w0.x; acc[1][0].y += x1 * w0.y; acc[1][0].z += x1 * w0.z; acc[1][0].w += x1 * w0.w;
            acc[1][1].x += x1 * w1.x; acc[1][1].y += x1 * w1.y; acc[1][1].z += x1 * w1.z; acc[1][1].w += x1 * w1.w;
            acc[1][2].x += x1 * w2.x; acc[1][2].y += x1 * w2.y; acc[1][2].z += x1 * w2.z; acc[1][2].w += x1 * w2.w;
            acc[1][3].x += x1 * w3.x; acc[1][3].y += x1 * w3.y; acc[1][3].z += x1 * w3.z; acc[1][3].w += x1 * w3.w;
            acc[2][0].x += x2 * w0.x; acc[2][0].y += x2 * w0.y; acc[2][0].z += x2 * w0.z; acc[2][0].w += x2 * w0.w;
            acc[2][1].x += x2 * w1.x; acc[2][1].y += x2 * w1.y; acc[2][1].z += x2 * w1.z; acc[2][1].w += x2 * w1.w;
            acc[2][2].x += x2 * w2.x; acc[2][2].y += x2 * w2.y; acc[2][2].z += x2 * w2.z; acc[2][2].w += x2 * w2.w;
            acc[2][3].x += x2 * w3.x; acc[2][3].y += x2 * w3.y; acc[2][3].z += x2 * w3.z; acc[2][3].w += x2 * w3.w;
            acc[3][0].x += x3 * w0.x; acc[3][0].y += x3 * w0.y; acc[3][0].z += x3 * w0.z; acc[3][0].w += x3 * w0.w;
            acc[3][1].x += x3 * w1.x; acc[3][1].y += x3 * w1.y; acc[3][1].z += x3 * w1.z; acc[3][1].w += x3 * w1.w;
            acc[3][2].x += x3 * w2.x; acc[3][2].y += x3 * w2.y; acc[3][2].z += x3 * w2.z; acc[3][2].w += x3 * w2.w;
            acc[3][3].x += x3 * w3.x; acc[3][3].y += x3 * w3.y; acc[3][3].z += x3 * w3.z; acc[3][3].w += x3 * w3.w;
        }
        if (d < 8) {
            float4* wn = (float4*)wb[(d + 1) & 1];
            wn[t] = pf0; wn[t + 256] = pf1;
        }
        __syncthreads();
    }

    if (cell < 49) {
        float* outp = p2 + (size_t)b * 3136 + cell * 64 + cg * 16;
        #pragma unroll
        for (int q = 0; q < 4; ++q) {
            float4 bs = *(const float4*)(b2 + cg * 16 + q * 4);
            float4 m = make_float4(-1e30f, -1e30f, -1e30f, -1e30f);
            #pragma unroll
            for (int p = 0; p < 4; ++p) {
                float4 v;
                v.x = elu1(acc[p][q].x + bs.x);
                v.y = elu1(acc[p][q].y + bs.y);
                v.z = elu1(acc[p][q].z + bs.z);
                v.w = elu1(acc[p][q].w + bs.w);
                m.x = fmaxf(m.x, v.x); m.y = fmaxf(m.y, v.y);
                m.z = fmaxf(m.z, v.z); m.w = fmaxf(m.w, v.w);
            }
            *(float4*)(outp + q * 4) = m;
        }
    }
}

// ============ Kernel 3a: fc1 split-K GEMM. 64x64 tile, BK=16, KS=8 ============
__global__ __launch_bounds__(256) void k3a_fc1(
    const float* __restrict__ A, const float* __restrict__ B,
    float* __restrict__ part) {
    __shared__ float As[16 * 64];
    __shared__ float Bs[16 * 64];
    const int t = threadIdx.x;
    const int tx = t & 15, ty = t >> 4;
    const int n0 = blockIdx.x * 64, m0 = blockIdx.y * 64, kz = blockIdx.z;
    const int nchunk = (kz < 4) ? 25 : 24;                 // 16-float chunks
    const int c0 = (kz < 4) ? kz * 25 : 100 + (kz - 4) * 24;

    const float* Abase = A + (size_t)m0 * 3136 + c0 * 16;
    const float* Bbase = B + (size_t)c0 * 16 * 512 + n0;

    float4 accr[4];
    #pragma unroll
    for (int r = 0; r < 4; ++r) accr[r] = make_float4(0.f, 0.f, 0.f, 0.f);

    const int ma = t >> 2, kqa = t & 3;     // A staging role
    const int kb = t >> 4, n4 = t & 15;     // B staging role

    for (int kk = 0; kk < nchunk; ++kk) {
        float4 av = *(const float4*)(Abase + (size_t)ma * 3136 + kk * 16 + kqa * 4);
        float4 bv = *(const float4*)(Bbase + (size_t)(kk * 16 + kb) * 512 + n4 * 4);
        As[(kqa * 4 + 0) * 64 + ma] = av.x;
        As[(kqa * 4 + 1) * 64 + ma] = av.y;
        As[(kqa * 4 + 2) * 64 + ma] = av.z;
        As[(kqa * 4 + 3) * 64 + ma] = av.w;
        *(float4*)&Bs[kb * 64 + n4 * 4] = bv;
        __syncthreads();
        #pragma unroll
        for (int k = 0; k < 16; ++k) {
            float4 a4 = *(const float4*)&As[k * 64 + ty * 4];
            float4 b4 = *(const float4*)&Bs[k * 64 + tx * 4];
            accr[0].x += a4.x * b4.x; accr[0].y += a4.x * b4.y; accr[0].z += a4.x * b4.z; accr[0].w += a4.x * b4.w;
            accr[1].x += a4.y * b4.x; accr[1].y += a4.y * b4.y; accr[1].z += a4.y * b4.z; accr[1].w += a4.y * b4.w;
            accr[2].x += a4.z * b4.x; accr[2].y += a4.z * b4.y; accr[2].z += a4.z * b4.z; accr[2].w += a4.z * b4.w;
            accr[3].x += a4.w * b4.x; accr[3].y += a4.w * b4.y; accr[3].z += a4.w * b4.z; accr[3].w += a4.w * b4.w;
        }
        __syncthreads();
    }
    #pragma unroll
    for (int r = 0; r < 4; ++r)
        *(float4*)(part + ((size_t)kz * 512 + m0 + ty * 4 + r) * 512 + n0 + tx * 4) = accr[r];
}

// ============ Kernel 3b: reduce partials + bias + ELU ============
__global__ __launch_bounds__(256) void k3b_reduce(
    const float* __restrict__ part, const float* __restrict__ bias,
    float* __restrict__ h3) {
    int gid = blockIdx.x * 256 + threadIdx.x;      // 0..65535 float4s
    const float4* p4 = (const float4*)part;
    float4 s = make_float4(0.f, 0.f, 0.f, 0.f);
    #pragma unroll
    for (int kz = 0; kz < 8; ++kz) {
        float4 v = p4[(size_t)kz * 65536 + gid];
        s.x += v.x; s.y += v.y; s.z += v.z; s.w += v.w;
    }
    float4 b4 = *(const float4*)(bias + (gid & 127) * 4);
    s.x += b4.x; s.y += b4.y; s.z += b4.z; s.w += b4.w;
    ((float4*)h3)[gid] = elu4(s);
}

// ============ Kernel 4: fc2 (512->10) + ELU + log_softmax ============
__global__ __launch_bounds__(256) void k4_fc2_lsm(
    const float* __restrict__ h, const float* __restrict__ w,
    const float* __restrict__ bias, float* __restrict__ out) {
    const int t = threadIdx.x, lane = t & 63;
    const int wv = (blockIdx.x * 256 + t) >> 6;   // global wave id 0..63
    float wl[8][10];
    #pragma unroll
    for (int j = 0; j < 8; ++j)
        #pragma unroll
        for (int o = 0; o < 10; ++o) wl[j][o] = w[(lane + 64 * j) * 10 + o];
    float bo[10];
    #pragma unroll
    for (int o = 0; o < 10; ++o) bo[o] = bias[o];

    for (int row = wv; row < 512; row += 64) {
        float acc[10];
        #pragma unroll
        for (int o = 0; o < 10; ++o) acc[o] = 0.f;
        #pragma unroll
        for (int j = 0; j < 8; ++j) {
            float hv = h[(size_t)row * 512 + lane + 64 * j];
            #pragma unroll
            for (int o = 0; o < 10; ++o) acc[o] += hv * wl[j][o];
        }
        #pragma unroll
        for (int s = 32; s; s >>= 1)
            #pragma unroll
            for (int o = 0; o < 10; ++o) acc[o] += __shfl_xor(acc[o], s, 64);
        float v[10], m = -1e30f;
        #pragma unroll
        for (int o = 0; o < 10; ++o) { v[o] = elu1(acc[o] + bo[o]); m = fmaxf(m, v[o]); }
        float ssum = 0.f;
        #pragma unroll
        for (int o = 0; o < 10; ++o) ssum += expf(v[o] - m);
        float lse = m + logf(ssum);
        if (lane < 10) {
            float val = v[0];
            #pragma unroll
            for (int o = 1; o < 10; ++o) val = (lane == o) ? v[o] : val;
            out[(size_t)row * 10 + lane] = val - lse;
        }
    }
}

extern "C" void kernel_launch(void* const* d_in, const int* in_sizes, int n_in,
                              void* d_out, int out_size, void* d_ws, size_t ws_size,
                              hipStream_t stream) {
    const float* x     = (const float*)d_in[0];
    const float* W1    = (const float*)d_in[3];
    const float* root1 = (const float*)d_in[4];
    const float* b1v   = (const float*)d_in[5];
    const float* W2    = (const float*)d_in[6];
    const float* root2 = (const float*)d_in[7];
    const float* b2v   = (const float*)d_in[8];
    const float* fc1w  = (const float*)d_in[9];
    const float* fc1b  = (const float*)d_in[10];
    const float* fc2w  = (const float*)d_in[11];
    const float* fc2b  = (const float*)d_in[12];

    float* ws = (float*)d_ws;
    float* p1 = ws;                                   // 512*196*32 = 3,211,264 f
    float* p2 = p1 + (size_t)BATCH * 196 * 32;        // 512*49*64  = 1,605,632 f
    float* h3 = p2 + (size_t)BATCH * 49 * 64;         // 512*512    =   262,144 f
    float* part = p1;                                 // alias: p1 dead after k2

    k1_conv1_pool<<<dim3(BATCH), 256, 0, stream>>>(x, W1, root1, b1v, p1);
    k2_conv2_pool<<<dim3(BATCH), 256, 0, stream>>>(p1, W2, root2, b2v, p2);
    k3a_fc1<<<dim3(8, 8, 8), 256, 0, stream>>>(p2, fc1w, part);
    k3b_reduce<<<dim3(256), 256, 0, stream>>>(part, fc1b, h3);
    k4_fc2_lsm<<<dim3(16), 256, 0, stream>>>(h3, fc2w, fc2b, (float*)d_out);
}